// Round 1
// baseline (3702.069 us; speedup 1.0000x reference)
//
#include <hip/hip_runtime.h>
#include <math.h>

#define NN 100000
#define EE 800000
#define DH 128
#define NL 16

// ---------------- CSR build ----------------
__global__ void k_hist(const int* __restrict__ row, int* __restrict__ cnt) {
    int e = blockIdx.x * 256 + threadIdx.x;
    if (e < EE) atomicAdd(&cnt[row[e]], 1);
}

__global__ void k_scan1(const int* __restrict__ cnt, int* __restrict__ rp, int* __restrict__ part) {
    __shared__ int buf[512];
    int tid = threadIdx.x;
    int i = blockIdx.x * 512 + tid;
    int v = (i < NN) ? cnt[i] : 0;
    buf[tid] = v;
    __syncthreads();
    for (int off = 1; off < 512; off <<= 1) {
        int x = (tid >= off) ? buf[tid - off] : 0;
        __syncthreads();
        buf[tid] += x;
        __syncthreads();
    }
    if (i < NN) rp[i] = buf[tid] - v;      // block-local exclusive
    if (tid == 511) part[blockIdx.x] = buf[511];
}

__global__ void k_scan2(int* __restrict__ part, int nparts) {
    __shared__ int buf[256];
    int tid = threadIdx.x;
    int v = (tid < nparts) ? part[tid] : 0;
    buf[tid] = v;
    __syncthreads();
    for (int off = 1; off < 256; off <<= 1) {
        int x = (tid >= off) ? buf[tid - off] : 0;
        __syncthreads();
        buf[tid] += x;
        __syncthreads();
    }
    if (tid < nparts) part[tid] = buf[tid] - v;  // exclusive across blocks
}

__global__ void k_scan3(int* __restrict__ rp, const int* __restrict__ part) {
    int i = blockIdx.x * 512 + threadIdx.x;
    if (i < NN) rp[i] += part[blockIdx.x];
    if (i == 0) rp[NN] = EE;
}

__global__ void k_fill(const int* __restrict__ row, const int* __restrict__ col,
                       const float* __restrict__ w, const int* __restrict__ rp,
                       int* __restrict__ fil, int* __restrict__ cols_s, float* __restrict__ ws_s) {
    int e = blockIdx.x * 256 + threadIdx.x;
    if (e >= EE) return;
    int r = row[e];
    int pos = rp[r] + atomicAdd(&fil[r], 1);
    cols_s[pos] = col[e];
    ws_s[pos] = w[e];
}

// ---------------- SpMM + initial-residual mix: a = 0.9*A@h + 0.1*x0 ----------------
// one wave per node; lane holds 2 features (float2 -> 512B coalesced row reads)
__global__ __launch_bounds__(256) void k_spmm(const float* __restrict__ h, const float* __restrict__ x0,
                                              const int* __restrict__ rp, const int* __restrict__ cols_s,
                                              const float* __restrict__ ws_s, float* __restrict__ a) {
    int node = blockIdx.x * 4 + (threadIdx.x >> 6);
    int lane = threadIdx.x & 63;
    const float2 xv = *(const float2*)&x0[node * DH + lane * 2];
    float2 acc;
    acc.x = 0.1f * xv.x;
    acc.y = 0.1f * xv.y;
    int s = rp[node], e = rp[node + 1];
    for (int i = s; i < e; ++i) {
        int c = cols_s[i];
        float w = 0.9f * ws_s[i];
        const float2 v = *(const float2*)&h[c * DH + lane * 2];
        acc.x = fmaf(w, v.x, acc.x);
        acc.y = fmaf(w, v.y, acc.y);
    }
    *(float2*)&a[node * DH + lane * 2] = acc;
}

// ---------------- input GEMM: x0 = h = relu(X @ Win + bin) ----------------
// 64 rows x 128 cols per block, 8x4 per-thread tile, W in LDS, A from global (L1 broadcast)
__global__ __launch_bounds__(256) void k_lin_in(const float* __restrict__ X, const float* __restrict__ Win,
                                                const float* __restrict__ bin,
                                                float* __restrict__ x0, float* __restrict__ h) {
    __shared__ float Bs[DH * DH];
    int tid = threadIdx.x;
    float4* Bs4 = (float4*)Bs;
    const float4* W4 = (const float4*)Win;
    for (int i = tid; i < DH * DH / 4; i += 256) Bs4[i] = W4[i];
    __syncthreads();

    int col_q = tid & 31, row_q = tid >> 5;
    int j0 = col_q * 4;
    int r0 = blockIdx.x * 64 + row_q * 8;
    const float4* Ar[8];
#pragma unroll
    for (int r = 0; r < 8; ++r) {
        int rc = r0 + r;
        if (rc > NN - 1) rc = NN - 1;
        Ar[r] = (const float4*)(X + (size_t)rc * DH);
    }
    float acc[8][4];
#pragma unroll
    for (int r = 0; r < 8; ++r)
        for (int c = 0; c < 4; ++c) acc[r][c] = 0.f;

    for (int k4 = 0; k4 < 32; ++k4) {
        float4 b0 = Bs4[(k4 * 4 + 0) * 32 + col_q];
        float4 b1 = Bs4[(k4 * 4 + 1) * 32 + col_q];
        float4 b2 = Bs4[(k4 * 4 + 2) * 32 + col_q];
        float4 b3 = Bs4[(k4 * 4 + 3) * 32 + col_q];
#pragma unroll
        for (int r = 0; r < 8; ++r) {
            float4 av = Ar[r][k4];
            acc[r][0] = fmaf(av.w, b3.x, fmaf(av.z, b2.x, fmaf(av.y, b1.x, fmaf(av.x, b0.x, acc[r][0]))));
            acc[r][1] = fmaf(av.w, b3.y, fmaf(av.z, b2.y, fmaf(av.y, b1.y, fmaf(av.x, b0.y, acc[r][1]))));
            acc[r][2] = fmaf(av.w, b3.z, fmaf(av.z, b2.z, fmaf(av.y, b1.z, fmaf(av.x, b0.z, acc[r][2]))));
            acc[r][3] = fmaf(av.w, b3.w, fmaf(av.z, b2.w, fmaf(av.y, b1.w, fmaf(av.x, b0.w, acc[r][3]))));
        }
    }
    float4 bias = *(const float4*)&bin[j0];
#pragma unroll
    for (int r = 0; r < 8; ++r) {
        int row = r0 + r;
        if (row < NN) {
            float4 o;
            o.x = fmaxf(acc[r][0] + bias.x, 0.f);
            o.y = fmaxf(acc[r][1] + bias.y, 0.f);
            o.z = fmaxf(acc[r][2] + bias.z, 0.f);
            o.w = fmaxf(acc[r][3] + bias.w, 0.f);
            *(float4*)&x0[row * DH + j0] = o;
            *(float4*)&h[row * DH + j0] = o;
        }
    }
}

// ---------------- layer GEMM: a <- a @ ((1-beta)I + beta*W), in-place, + BN stats ----------------
__global__ __launch_bounds__(256) void k_gemm_layer(const float* A, float* Aout,
                                                    const float* __restrict__ Wl, float beta,
                                                    float* __restrict__ stats) {
    __shared__ float Bs[DH * DH];
    int tid = threadIdx.x;
    float4* Bs4 = (float4*)Bs;
    const float4* W4 = (const float4*)Wl;
    float ob = 1.0f - beta;
    for (int i = tid; i < DH * DH / 4; i += 256) {
        float4 v = W4[i];
        int k = i >> 5, j4 = (i & 31) << 2;
        float vv[4] = {v.x * beta, v.y * beta, v.z * beta, v.w * beta};
        int d = k - j4;
        if (d >= 0 && d < 4) vv[d] += ob;
        Bs4[i] = make_float4(vv[0], vv[1], vv[2], vv[3]);
    }
    __syncthreads();

    int col_q = tid & 31, row_q = tid >> 5;
    int j0 = col_q * 4;
    int r0 = blockIdx.x * 64 + row_q * 8;
    const float4* Ar[8];
#pragma unroll
    for (int r = 0; r < 8; ++r) {
        int rc = r0 + r;
        if (rc > NN - 1) rc = NN - 1;
        Ar[r] = (const float4*)(A + (size_t)rc * DH);
    }
    float acc[8][4];
#pragma unroll
    for (int r = 0; r < 8; ++r)
        for (int c = 0; c < 4; ++c) acc[r][c] = 0.f;

    for (int k4 = 0; k4 < 32; ++k4) {
        float4 b0 = Bs4[(k4 * 4 + 0) * 32 + col_q];
        float4 b1 = Bs4[(k4 * 4 + 1) * 32 + col_q];
        float4 b2 = Bs4[(k4 * 4 + 2) * 32 + col_q];
        float4 b3 = Bs4[(k4 * 4 + 3) * 32 + col_q];
#pragma unroll
        for (int r = 0; r < 8; ++r) {
            float4 av = Ar[r][k4];
            acc[r][0] = fmaf(av.w, b3.x, fmaf(av.z, b2.x, fmaf(av.y, b1.x, fmaf(av.x, b0.x, acc[r][0]))));
            acc[r][1] = fmaf(av.w, b3.y, fmaf(av.z, b2.y, fmaf(av.y, b1.y, fmaf(av.x, b0.y, acc[r][1]))));
            acc[r][2] = fmaf(av.w, b3.z, fmaf(av.z, b2.z, fmaf(av.y, b1.z, fmaf(av.x, b0.z, acc[r][2]))));
            acc[r][3] = fmaf(av.w, b3.w, fmaf(av.z, b2.w, fmaf(av.y, b1.w, fmaf(av.x, b0.w, acc[r][3]))));
        }
    }
    // in-place store is safe: each wave reads exactly the rows it writes, lockstep
#pragma unroll
    for (int r = 0; r < 8; ++r) {
        int row = r0 + r;
        if (row < NN)
            *(float4*)&Aout[row * DH + j0] = make_float4(acc[r][0], acc[r][1], acc[r][2], acc[r][3]);
    }
    // BN stats: per-block reduce in LDS (reuse Bs), then 256 atomics
    __syncthreads();
    float* red = Bs;  // [8][256]: j -> sum, 128+j -> sumsq
    float s[4] = {0, 0, 0, 0}, s2[4] = {0, 0, 0, 0};
#pragma unroll
    for (int r = 0; r < 8; ++r) {
        if (r0 + r < NN) {
#pragma unroll
            for (int c = 0; c < 4; ++c) {
                float v = acc[r][c];
                s[c] += v;
                s2[c] += v * v;
            }
        }
    }
#pragma unroll
    for (int c = 0; c < 4; ++c) {
        red[row_q * 256 + j0 + c] = s[c];
        red[row_q * 256 + 128 + j0 + c] = s2[c];
    }
    __syncthreads();
    {
        float tot = 0;
#pragma unroll
        for (int q = 0; q < 8; ++q) tot += red[q * 256 + tid & 255];  // tid < 256 always
        // note: tid&255 == tid for blockDim 256
        atomicAdd(&stats[tid], tot);
    }
}

// ---------------- BN finalize: scale/shift per feature ----------------
__global__ void k_bn(const float* __restrict__ stats, const float* __restrict__ gamma,
                     const float* __restrict__ bbeta, float* __restrict__ ss) {
    int j = threadIdx.x;  // 128
    float s = stats[j], s2 = stats[128 + j];
    float mu = s * (1.0f / NN);
    float var = s2 * (1.0f / NN) - mu * mu;
    if (var < 0.f) var = 0.f;
    float sc = gamma[j] * rsqrtf(var + 1e-5f);
    ss[j] = sc;
    ss[128 + j] = bbeta[j] - mu * sc;
}

// ---------------- h = relu(a*scale + shift + h) ----------------
__global__ __launch_bounds__(256) void k_update(const float* __restrict__ a, float* __restrict__ h,
                                                const float* __restrict__ ss) {
    int idx = blockIdx.x * 256 + threadIdx.x;  // float4 index, 3.2M total
    int j0 = (idx & 31) * 4;
    float4 av = ((const float4*)a)[idx];
    float4 hv = ((float4*)h)[idx];
    float4 sc = *(const float4*)&ss[j0];
    float4 sh = *(const float4*)&ss[128 + j0];
    float4 o;
    o.x = fmaxf(fmaf(av.x, sc.x, sh.x) + hv.x, 0.f);
    o.y = fmaxf(fmaf(av.y, sc.y, sh.y) + hv.y, 0.f);
    o.z = fmaxf(fmaf(av.z, sc.z, sh.z) + hv.z, 0.f);
    o.w = fmaxf(fmaf(av.w, sc.w, sh.w) + hv.w, 0.f);
    ((float4*)h)[idx] = o;
}

// ---------------- output GEMM: out = h @ Wout + bout  (cols padded 40->64) ----------------
__global__ __launch_bounds__(256) void k_gemm_out(const float* __restrict__ A, const float* __restrict__ Wout,
                                                  const float* __restrict__ bout, float* __restrict__ out) {
    __shared__ float Bs[DH * 64];
    int tid = threadIdx.x;
    for (int i = tid; i < DH * 64; i += 256) {
        int k = i >> 6, j = i & 63;
        Bs[i] = (j < 40) ? Wout[k * 40 + j] : 0.f;
    }
    __syncthreads();

    int col_q = tid & 15, row_q = tid >> 4;
    int j0 = col_q * 4;
    int r0 = blockIdx.x * 128 + row_q * 8;
    const float4* Bs4 = (const float4*)Bs;
    const float4* Ar[8];
#pragma unroll
    for (int r = 0; r < 8; ++r) {
        int rc = r0 + r;
        if (rc > NN - 1) rc = NN - 1;
        Ar[r] = (const float4*)(A + (size_t)rc * DH);
    }
    float acc[8][4];
#pragma unroll
    for (int r = 0; r < 8; ++r)
        for (int c = 0; c < 4; ++c) acc[r][c] = 0.f;

    for (int k4 = 0; k4 < 32; ++k4) {
        float4 b0 = Bs4[(k4 * 4 + 0) * 16 + col_q];
        float4 b1 = Bs4[(k4 * 4 + 1) * 16 + col_q];
        float4 b2 = Bs4[(k4 * 4 + 2) * 16 + col_q];
        float4 b3 = Bs4[(k4 * 4 + 3) * 16 + col_q];
#pragma unroll
        for (int r = 0; r < 8; ++r) {
            float4 av = Ar[r][k4];
            acc[r][0] = fmaf(av.w, b3.x, fmaf(av.z, b2.x, fmaf(av.y, b1.x, fmaf(av.x, b0.x, acc[r][0]))));
            acc[r][1] = fmaf(av.w, b3.y, fmaf(av.z, b2.y, fmaf(av.y, b1.y, fmaf(av.x, b0.y, acc[r][1]))));
            acc[r][2] = fmaf(av.w, b3.z, fmaf(av.z, b2.z, fmaf(av.y, b1.z, fmaf(av.x, b0.z, acc[r][2]))));
            acc[r][3] = fmaf(av.w, b3.w, fmaf(av.z, b2.w, fmaf(av.y, b1.w, fmaf(av.x, b0.w, acc[r][3]))));
        }
    }
#pragma unroll
    for (int r = 0; r < 8; ++r) {
        int row = r0 + r;
        if (row < NN) {
#pragma unroll
            for (int c = 0; c < 4; ++c) {
                int j = j0 + c;
                if (j < 40) out[row * 40 + j] = acc[r][c] + bout[j];
            }
        }
    }
}

extern "C" void kernel_launch(void* const* d_in, const int* in_sizes, int n_in,
                              void* d_out, int out_size, void* d_ws, size_t ws_size,
                              hipStream_t stream) {
    const float* x = (const float*)d_in[0];
    const float* ew = (const float*)d_in[1];
    const float* Win = (const float*)d_in[2];
    const float* bin = (const float*)d_in[3];
    const float* convW = (const float*)d_in[4];
    const float* gamma = (const float*)d_in[5];
    const float* bbeta = (const float*)d_in[6];
    const float* Wout = (const float*)d_in[7];
    const float* bout = (const float*)d_in[8];
    const int* erow = (const int*)d_in[9];
    const int* ecol = (const int*)d_in[10];
    float* out = (float*)d_out;

    // workspace carve-up (~161 MB)
    char* wsp = (char*)d_ws;
    size_t off = 0;
    auto alloc = [&](size_t bytes) -> void* {
        void* p = wsp + off;
        off += (bytes + 255) & ~(size_t)255;
        return p;
    };
    float* x0 = (float*)alloc((size_t)NN * DH * 4);
    float* h = (float*)alloc((size_t)NN * DH * 4);
    float* a = (float*)alloc((size_t)NN * DH * 4);
    int* rp = (int*)alloc((NN + 1) * 4);
    int* cnt = (int*)alloc(NN * 4);
    int* fil = (int*)alloc(NN * 4);
    int* cols_s = (int*)alloc(EE * 4);
    float* ws_s = (float*)alloc(EE * 4);
    int* part = (int*)alloc(256 * 4);
    float* stats = (float*)alloc(NL * 256 * 4);
    float* ss = (float*)alloc(NL * 256 * 4);

    hipMemsetAsync(cnt, 0, NN * 4, stream);
    hipMemsetAsync(fil, 0, NN * 4, stream);
    hipMemsetAsync(stats, 0, NL * 256 * 4, stream);

    // CSR build (graph identical across layers; rebuilt every call — no static state)
    k_hist<<<3125, 256, 0, stream>>>(erow, cnt);
    k_scan1<<<196, 512, 0, stream>>>(cnt, rp, part);
    k_scan2<<<1, 256, 0, stream>>>(part, 196);
    k_scan3<<<196, 512, 0, stream>>>(rp, part);
    k_fill<<<3125, 256, 0, stream>>>(erow, ecol, ew, rp, fil, cols_s, ws_s);

    k_lin_in<<<1563, 256, 0, stream>>>(x, Win, bin, x0, h);

    for (int l = 0; l < NL; ++l) {
        float beta = logf(0.5f / (float)(l + 1) + 1.0f);
        k_spmm<<<25000, 256, 0, stream>>>(h, x0, rp, cols_s, ws_s, a);
        k_gemm_layer<<<1563, 256, 0, stream>>>(a, a, convW + (size_t)l * DH * DH, beta, stats + l * 256);
        k_bn<<<1, 128, 0, stream>>>(stats + l * 256, gamma + l * DH, bbeta + l * DH, ss + l * 256);
        k_update<<<12500, 256, 0, stream>>>(a, h, ss + l * 256);
    }
    k_gemm_out<<<782, 256, 0, stream>>>(h, Wout, bout, out);
}

// Round 2
// 2757.255 us; speedup vs baseline: 1.3427x; 1.3427x over previous
//
#include <hip/hip_runtime.h>
#include <math.h>

#define NN 100000
#define EE 800000
#define DH 128
#define NL 16

typedef __bf16 bf16x8 __attribute__((ext_vector_type(8)));
typedef __bf16 bf16x2 __attribute__((ext_vector_type(2)));
typedef float f32x4 __attribute__((ext_vector_type(4)));

// ---------------- CSR build ----------------
__global__ void k_hist(const int* __restrict__ row, int* __restrict__ cnt) {
    int e = blockIdx.x * 256 + threadIdx.x;
    if (e < EE) atomicAdd(&cnt[row[e]], 1);
}

__global__ void k_scan1(const int* __restrict__ cnt, int* __restrict__ rp, int* __restrict__ part) {
    __shared__ int buf[512];
    int tid = threadIdx.x;
    int i = blockIdx.x * 512 + tid;
    int v = (i < NN) ? cnt[i] : 0;
    buf[tid] = v;
    __syncthreads();
    for (int off = 1; off < 512; off <<= 1) {
        int x = (tid >= off) ? buf[tid - off] : 0;
        __syncthreads();
        buf[tid] += x;
        __syncthreads();
    }
    if (i < NN) rp[i] = buf[tid] - v;
    if (tid == 511) part[blockIdx.x] = buf[511];
}

__global__ void k_scan2(int* __restrict__ part, int nparts) {
    __shared__ int buf[256];
    int tid = threadIdx.x;
    int v = (tid < nparts) ? part[tid] : 0;
    buf[tid] = v;
    __syncthreads();
    for (int off = 1; off < 256; off <<= 1) {
        int x = (tid >= off) ? buf[tid - off] : 0;
        __syncthreads();
        buf[tid] += x;
        __syncthreads();
    }
    if (tid < nparts) part[tid] = buf[tid] - v;
}

__global__ void k_scan3(int* __restrict__ rp, const int* __restrict__ part) {
    int i = blockIdx.x * 512 + threadIdx.x;
    if (i < NN) rp[i] += part[blockIdx.x];
    if (i == 0) rp[NN] = EE;
}

__global__ void k_fill(const int* __restrict__ row, const int* __restrict__ col,
                       const float* __restrict__ w, const int* __restrict__ rp,
                       int* __restrict__ fil, int2* __restrict__ ep) {
    int e = blockIdx.x * 256 + threadIdx.x;
    if (e >= EE) return;
    int r = row[e];
    int pos = rp[r] + atomicAdd(&fil[r], 1);
    ep[pos] = make_int2(col[e], __float_as_int(w[e]));
}

// ---------------- SpMM + mix: a = 0.9*(A@h) + 0.1*x0 ; 4-way MLP unroll ----------------
__global__ __launch_bounds__(256) void k_spmm(const float* __restrict__ h, const float* __restrict__ x0,
                                              const int* __restrict__ rp, const int2* __restrict__ ep,
                                              float* __restrict__ a) {
    int node = blockIdx.x * 4 + (threadIdx.x >> 6);
    int lane = threadIdx.x & 63;
    int fo = lane * 2;
    float2 acc = make_float2(0.f, 0.f);
    int s = rp[node], e = rp[node + 1];
    int i = s;
    for (; i + 3 < e; i += 4) {
        int2 p0 = ep[i], p1 = ep[i + 1], p2 = ep[i + 2], p3 = ep[i + 3];
        float2 v0 = *(const float2*)&h[(size_t)p0.x * DH + fo];
        float2 v1 = *(const float2*)&h[(size_t)p1.x * DH + fo];
        float2 v2 = *(const float2*)&h[(size_t)p2.x * DH + fo];
        float2 v3 = *(const float2*)&h[(size_t)p3.x * DH + fo];
        float w0 = __int_as_float(p0.y), w1 = __int_as_float(p1.y);
        float w2 = __int_as_float(p2.y), w3 = __int_as_float(p3.y);
        acc.x = fmaf(w0, v0.x, acc.x); acc.y = fmaf(w0, v0.y, acc.y);
        acc.x = fmaf(w1, v1.x, acc.x); acc.y = fmaf(w1, v1.y, acc.y);
        acc.x = fmaf(w2, v2.x, acc.x); acc.y = fmaf(w2, v2.y, acc.y);
        acc.x = fmaf(w3, v3.x, acc.x); acc.y = fmaf(w3, v3.y, acc.y);
    }
    for (; i < e; ++i) {
        int2 p = ep[i];
        float w = __int_as_float(p.y);
        float2 v = *(const float2*)&h[(size_t)p.x * DH + fo];
        acc.x = fmaf(w, v.x, acc.x);
        acc.y = fmaf(w, v.y, acc.y);
    }
    float2 xv = *(const float2*)&x0[(size_t)node * DH + fo];
    float2 o;
    o.x = fmaf(0.9f, acc.x, 0.1f * xv.x);
    o.y = fmaf(0.9f, acc.y, 0.1f * xv.y);
    *(float2*)&a[(size_t)node * DH + fo] = o;
}

// Split a float into bf16 hi + lo
__device__ inline void split8(const float* p, bf16x8& hi, bf16x8& lo) {
    f32x4 v0 = *(const f32x4*)p;
    f32x4 v1 = *(const f32x4*)(p + 4);
#pragma unroll
    for (int j = 0; j < 4; ++j) {
        __bf16 h0 = (__bf16)v0[j];
        hi[j] = h0;
        lo[j] = (__bf16)(v0[j] - (float)h0);
        __bf16 h1 = (__bf16)v1[j];
        hi[4 + j] = h1;
        lo[4 + j] = (__bf16)(v1[j] - (float)h1);
    }
}

#define MFMA(a, b, c) __builtin_amdgcn_mfma_f32_16x16x32_bf16(a, b, c, 0, 0, 0)

// ---------------- layer GEMM via MFMA: a <- a @ ((1-beta)I + beta*W), in-place, + BN stats ----------------
// block = 256 thr (4 waves), 64 rows; A fp32 from global split on the fly; M split bf16 in LDS.
__global__ __launch_bounds__(256) void k_gemm_mfma(const float* __restrict__ A, float* __restrict__ Aout,
                                                   const float* __restrict__ W, float beta,
                                                   float* __restrict__ stats) {
    __shared__ __bf16 Bt[2][DH * 136];  // [hi/lo][col j][k], k-stride 1, col-stride 136
    __shared__ float red[2][4][DH];
    int tid = threadIdx.x;
    float ob = 1.0f - beta;
    for (int i = tid; i < DH * DH; i += 256) {
        int k = i >> 7, j = i & 127;
        float v = beta * W[i] + ((k == j) ? ob : 0.f);
        __bf16 hv = (__bf16)v;
        Bt[0][j * 136 + k] = hv;
        Bt[1][j * 136 + k] = (__bf16)(v - (float)hv);
    }
    __syncthreads();

    int wave = tid >> 6, lane = tid & 63;
    int n = lane & 15, quad = lane >> 4;
    int r0 = blockIdx.x * 64 + wave * 16;
    int arow = r0 + n;
    if (arow > NN - 1) arow = NN - 1;
    const float* pa = A + (size_t)arow * DH + quad * 8;

    f32x4 acc[8];
#pragma unroll
    for (int t = 0; t < 8; ++t) acc[t] = (f32x4){0.f, 0.f, 0.f, 0.f};

#pragma unroll
    for (int ks = 0; ks < 4; ++ks) {
        bf16x8 ah, al;
        split8(pa + ks * 32, ah, al);
        int kb = ks * 32 + quad * 8;
#pragma unroll
        for (int t = 0; t < 8; ++t) {
            bf16x8 bh = *(const bf16x8*)&Bt[0][(t * 16 + n) * 136 + kb];
            bf16x8 bl = *(const bf16x8*)&Bt[1][(t * 16 + n) * 136 + kb];
            acc[t] = MFMA(ah, bh, acc[t]);
            acc[t] = MFMA(al, bh, acc[t]);
            acc[t] = MFMA(ah, bl, acc[t]);
        }
    }

    // epilogue: store fp32 + exact BN stats (shfl across quads, LDS across waves, atomics)
#pragma unroll
    for (int t = 0; t < 8; ++t) {
        float s = 0.f, q = 0.f;
#pragma unroll
        for (int r = 0; r < 4; ++r) {
            int row = r0 + quad * 4 + r;
            float v = acc[t][r];
            if (row < NN) {
                Aout[(size_t)row * DH + t * 16 + n] = v;
                s += v;
                q += v * v;
            }
        }
        s += __shfl_xor(s, 16); s += __shfl_xor(s, 32);
        q += __shfl_xor(q, 16); q += __shfl_xor(q, 32);
        if (quad == 0) {
            red[0][wave][t * 16 + n] = s;
            red[1][wave][t * 16 + n] = q;
        }
    }
    __syncthreads();
    {
        int which = tid >> 7, j = tid & 127;
        float tot = red[which][0][j] + red[which][1][j] + red[which][2][j] + red[which][3][j];
        atomicAdd(&stats[tid], tot);
    }
}

// ---------------- input GEMM via MFMA: x0 = relu(X @ Win + bin) ----------------
__global__ __launch_bounds__(256) void k_lin_in(const float* __restrict__ X, const float* __restrict__ Win,
                                                const float* __restrict__ bin, float* __restrict__ x0) {
    __shared__ __bf16 Bt[2][DH * 136];
    int tid = threadIdx.x;
    for (int i = tid; i < DH * DH; i += 256) {
        int k = i >> 7, j = i & 127;
        float v = Win[i];
        __bf16 hv = (__bf16)v;
        Bt[0][j * 136 + k] = hv;
        Bt[1][j * 136 + k] = (__bf16)(v - (float)hv);
    }
    __syncthreads();

    int wave = tid >> 6, lane = tid & 63;
    int n = lane & 15, quad = lane >> 4;
    int r0 = blockIdx.x * 64 + wave * 16;
    int arow = r0 + n;
    if (arow > NN - 1) arow = NN - 1;
    const float* pa = X + (size_t)arow * DH + quad * 8;

    f32x4 acc[8];
#pragma unroll
    for (int t = 0; t < 8; ++t) acc[t] = (f32x4){0.f, 0.f, 0.f, 0.f};

#pragma unroll
    for (int ks = 0; ks < 4; ++ks) {
        bf16x8 ah, al;
        split8(pa + ks * 32, ah, al);
        int kb = ks * 32 + quad * 8;
#pragma unroll
        for (int t = 0; t < 8; ++t) {
            bf16x8 bh = *(const bf16x8*)&Bt[0][(t * 16 + n) * 136 + kb];
            bf16x8 bl = *(const bf16x8*)&Bt[1][(t * 16 + n) * 136 + kb];
            acc[t] = MFMA(ah, bh, acc[t]);
            acc[t] = MFMA(al, bh, acc[t]);
            acc[t] = MFMA(ah, bl, acc[t]);
        }
    }

#pragma unroll
    for (int t = 0; t < 8; ++t) {
        float bj = bin[t * 16 + n];
#pragma unroll
        for (int r = 0; r < 4; ++r) {
            int row = r0 + quad * 4 + r;
            if (row < NN) {
                float v = fmaxf(acc[t][r] + bj, 0.f);
                x0[(size_t)row * DH + t * 16 + n] = v;
            }
        }
    }
}

// ---------------- output GEMM via MFMA: out = h @ Wout + bout (40 cols, 3 tiles of 16) ----------------
__global__ __launch_bounds__(256) void k_gemm_out(const float* __restrict__ A, const float* __restrict__ Wout,
                                                  const float* __restrict__ bout, float* __restrict__ out) {
    __shared__ __bf16 Bt[2][48 * 136];
    int tid = threadIdx.x;
    for (int i = tid; i < DH * 64; i += 256) {
        int k = i >> 6, j = i & 63;
        if (j < 48) {
            float v = (j < 40) ? Wout[k * 40 + j] : 0.f;
            __bf16 hv = (__bf16)v;
            Bt[0][j * 136 + k] = hv;
            Bt[1][j * 136 + k] = (__bf16)(v - (float)hv);
        }
    }
    __syncthreads();

    int wave = tid >> 6, lane = tid & 63;
    int n = lane & 15, quad = lane >> 4;
    int r0 = blockIdx.x * 64 + wave * 16;
    int arow = r0 + n;
    if (arow > NN - 1) arow = NN - 1;
    const float* pa = A + (size_t)arow * DH + quad * 8;

    f32x4 acc[3];
#pragma unroll
    for (int t = 0; t < 3; ++t) acc[t] = (f32x4){0.f, 0.f, 0.f, 0.f};

#pragma unroll
    for (int ks = 0; ks < 4; ++ks) {
        bf16x8 ah, al;
        split8(pa + ks * 32, ah, al);
        int kb = ks * 32 + quad * 8;
#pragma unroll
        for (int t = 0; t < 3; ++t) {
            bf16x8 bh = *(const bf16x8*)&Bt[0][(t * 16 + n) * 136 + kb];
            bf16x8 bl = *(const bf16x8*)&Bt[1][(t * 16 + n) * 136 + kb];
            acc[t] = MFMA(ah, bh, acc[t]);
            acc[t] = MFMA(al, bh, acc[t]);
            acc[t] = MFMA(ah, bl, acc[t]);
        }
    }

#pragma unroll
    for (int t = 0; t < 3; ++t) {
        int j = t * 16 + n;
        float bj = (j < 40) ? bout[j] : 0.f;
#pragma unroll
        for (int r = 0; r < 4; ++r) {
            int row = r0 + quad * 4 + r;
            if (row < NN && j < 40) out[(size_t)row * 40 + j] = acc[t][r] + bj;
        }
    }
}

// ---------------- BN finalize ----------------
__global__ void k_bn(const float* __restrict__ stats, const float* __restrict__ gamma,
                     const float* __restrict__ bbeta, float* __restrict__ ss) {
    int j = threadIdx.x;
    float s = stats[j], s2 = stats[128 + j];
    float mu = s * (1.0f / NN);
    float var = s2 * (1.0f / NN) - mu * mu;
    if (var < 0.f) var = 0.f;
    float sc = gamma[j] * rsqrtf(var + 1e-5f);
    ss[j] = sc;
    ss[128 + j] = bbeta[j] - mu * sc;
}

// ---------------- h_out = relu(a*scale + shift + h_in) ----------------
__global__ __launch_bounds__(256) void k_update(const float* __restrict__ a, const float* __restrict__ hin,
                                                float* __restrict__ hout, const float* __restrict__ ss) {
    int idx = blockIdx.x * 256 + threadIdx.x;
    int j0 = (idx & 31) * 4;
    float4 av = ((const float4*)a)[idx];
    float4 hv = ((const float4*)hin)[idx];
    float4 sc = *(const float4*)&ss[j0];
    float4 sh = *(const float4*)&ss[128 + j0];
    float4 o;
    o.x = fmaxf(fmaf(av.x, sc.x, sh.x) + hv.x, 0.f);
    o.y = fmaxf(fmaf(av.y, sc.y, sh.y) + hv.y, 0.f);
    o.z = fmaxf(fmaf(av.z, sc.z, sh.z) + hv.z, 0.f);
    o.w = fmaxf(fmaf(av.w, sc.w, sh.w) + hv.w, 0.f);
    ((float4*)hout)[idx] = o;
}

extern "C" void kernel_launch(void* const* d_in, const int* in_sizes, int n_in,
                              void* d_out, int out_size, void* d_ws, size_t ws_size,
                              hipStream_t stream) {
    const float* x = (const float*)d_in[0];
    const float* ew = (const float*)d_in[1];
    const float* Win = (const float*)d_in[2];
    const float* bin = (const float*)d_in[3];
    const float* convW = (const float*)d_in[4];
    const float* gamma = (const float*)d_in[5];
    const float* bbeta = (const float*)d_in[6];
    const float* Wout = (const float*)d_in[7];
    const float* bout = (const float*)d_in[8];
    const int* erow = (const int*)d_in[9];
    const int* ecol = (const int*)d_in[10];
    float* out = (float*)d_out;

    char* wsp = (char*)d_ws;
    size_t off = 0;
    auto alloc = [&](size_t bytes) -> void* {
        void* p = wsp + off;
        off += (bytes + 255) & ~(size_t)255;
        return p;
    };
    float* x0 = (float*)alloc((size_t)NN * DH * 4);
    float* h = (float*)alloc((size_t)NN * DH * 4);
    float* a = (float*)alloc((size_t)NN * DH * 4);
    int* rp = (int*)alloc((NN + 1) * 4);
    int* cnt = (int*)alloc(NN * 4);
    int* fil = (int*)alloc(NN * 4);
    int2* ep = (int2*)alloc((size_t)EE * 8);
    int* part = (int*)alloc(256 * 4);
    float* stats = (float*)alloc(NL * 256 * 4);
    float* ss = (float*)alloc(NL * 256 * 4);

    hipMemsetAsync(cnt, 0, NN * 4, stream);
    hipMemsetAsync(fil, 0, NN * 4, stream);
    hipMemsetAsync(stats, 0, NL * 256 * 4, stream);

    k_hist<<<3125, 256, 0, stream>>>(erow, cnt);
    k_scan1<<<196, 512, 0, stream>>>(cnt, rp, part);
    k_scan2<<<1, 256, 0, stream>>>(part, 196);
    k_scan3<<<196, 512, 0, stream>>>(rp, part);
    k_fill<<<3125, 256, 0, stream>>>(erow, ecol, ew, rp, fil, ep);

    k_lin_in<<<1563, 256, 0, stream>>>(x, Win, bin, x0);

    for (int l = 0; l < NL; ++l) {
        float beta = logf(0.5f / (float)(l + 1) + 1.0f);
        const float* hin = (l == 0) ? x0 : h;
        k_spmm<<<25000, 256, 0, stream>>>(hin, x0, rp, ep, a);
        k_gemm_mfma<<<1563, 256, 0, stream>>>(a, a, convW + (size_t)l * DH * DH, beta, stats + l * 256);
        k_bn<<<1, 128, 0, stream>>>(stats + l * 256, gamma + l * DH, bbeta + l * DH, ss + l * 256);
        k_update<<<12500, 256, 0, stream>>>(a, hin, h, ss + l * 256);
    }
    k_gemm_out<<<1563, 256, 0, stream>>>(h, Wout, bout, out);
}

// Round 3
// 2213.797 us; speedup vs baseline: 1.6723x; 1.2455x over previous
//
#include <hip/hip_runtime.h>
#include <math.h>

#define NN 100000
#define EE 800000
#define DH 128
#define NL 16

typedef __bf16 bf16x8 __attribute__((ext_vector_type(8)));
typedef __bf16 bf16x2 __attribute__((ext_vector_type(2)));
typedef float f32x4 __attribute__((ext_vector_type(4)));

// ---------------- CSR build ----------------
__global__ void k_hist(const int* __restrict__ row, int* __restrict__ cnt) {
    int e = blockIdx.x * 256 + threadIdx.x;
    if (e < EE) atomicAdd(&cnt[row[e]], 1);
}

__global__ void k_scan1(const int* __restrict__ cnt, int* __restrict__ rp, int* __restrict__ part) {
    __shared__ int buf[512];
    int tid = threadIdx.x;
    int i = blockIdx.x * 512 + tid;
    int v = (i < NN) ? cnt[i] : 0;
    buf[tid] = v;
    __syncthreads();
    for (int off = 1; off < 512; off <<= 1) {
        int x = (tid >= off) ? buf[tid - off] : 0;
        __syncthreads();
        buf[tid] += x;
        __syncthreads();
    }
    if (i < NN) rp[i] = buf[tid] - v;
    if (tid == 511) part[blockIdx.x] = buf[511];
}

__global__ void k_scan2(int* __restrict__ part, int nparts) {
    __shared__ int buf[256];
    int tid = threadIdx.x;
    int v = (tid < nparts) ? part[tid] : 0;
    buf[tid] = v;
    __syncthreads();
    for (int off = 1; off < 256; off <<= 1) {
        int x = (tid >= off) ? buf[tid - off] : 0;
        __syncthreads();
        buf[tid] += x;
        __syncthreads();
    }
    if (tid < nparts) part[tid] = buf[tid] - v;
}

__global__ void k_scan3(int* __restrict__ rp, const int* __restrict__ part) {
    int i = blockIdx.x * 512 + threadIdx.x;
    if (i < NN) rp[i] += part[blockIdx.x];
    if (i == 0) rp[NN] = EE;
}

__global__ void k_fill(const int* __restrict__ row, const int* __restrict__ col,
                       const float* __restrict__ w, const int* __restrict__ rp,
                       int* __restrict__ fil, int2* __restrict__ ep) {
    int e = blockIdx.x * 256 + threadIdx.x;
    if (e >= EE) return;
    int r = row[e];
    int pos = rp[r] + atomicAdd(&fil[r], 1);
    ep[pos] = make_int2(col[e], __float_as_int(w[e]));
}

// ---------------- SpMM + mix: a = 0.9*(Adj@h) + 0.1*x0 ; bf16 activations ----------------
// one wave per node, lane holds 2 features (bf16x2 = 4B -> 256B coalesced row reads)
__global__ __launch_bounds__(256) void k_spmm(const __bf16* __restrict__ h, const __bf16* __restrict__ x0,
                                              const int* __restrict__ rp, const int2* __restrict__ ep,
                                              __bf16* __restrict__ a) {
    int node = blockIdx.x * 4 + (threadIdx.x >> 6);
    int lane = threadIdx.x & 63;
    int fo = lane * 2;
    float2 acc = make_float2(0.f, 0.f);
    int s = rp[node], e = rp[node + 1];
    int i = s;
    for (; i + 3 < e; i += 4) {
        int2 p0 = ep[i], p1 = ep[i + 1], p2 = ep[i + 2], p3 = ep[i + 3];
        bf16x2 v0 = *(const bf16x2*)&h[(size_t)p0.x * DH + fo];
        bf16x2 v1 = *(const bf16x2*)&h[(size_t)p1.x * DH + fo];
        bf16x2 v2 = *(const bf16x2*)&h[(size_t)p2.x * DH + fo];
        bf16x2 v3 = *(const bf16x2*)&h[(size_t)p3.x * DH + fo];
        float w0 = __int_as_float(p0.y), w1 = __int_as_float(p1.y);
        float w2 = __int_as_float(p2.y), w3 = __int_as_float(p3.y);
        acc.x = fmaf(w0, (float)v0[0], acc.x); acc.y = fmaf(w0, (float)v0[1], acc.y);
        acc.x = fmaf(w1, (float)v1[0], acc.x); acc.y = fmaf(w1, (float)v1[1], acc.y);
        acc.x = fmaf(w2, (float)v2[0], acc.x); acc.y = fmaf(w2, (float)v2[1], acc.y);
        acc.x = fmaf(w3, (float)v3[0], acc.x); acc.y = fmaf(w3, (float)v3[1], acc.y);
    }
    for (; i < e; ++i) {
        int2 p = ep[i];
        float w = __int_as_float(p.y);
        bf16x2 v = *(const bf16x2*)&h[(size_t)p.x * DH + fo];
        acc.x = fmaf(w, (float)v[0], acc.x);
        acc.y = fmaf(w, (float)v[1], acc.y);
    }
    bf16x2 xv = *(const bf16x2*)&x0[(size_t)node * DH + fo];
    bf16x2 o;
    o[0] = (__bf16)fmaf(0.9f, acc.x, 0.1f * (float)xv[0]);
    o[1] = (__bf16)fmaf(0.9f, acc.y, 0.1f * (float)xv[1]);
    *(bf16x2*)&a[(size_t)node * DH + fo] = o;
}

// Split a float row-chunk into bf16 hi + lo (for fp32 input X only)
__device__ inline void split8(const float* p, bf16x8& hi, bf16x8& lo) {
    f32x4 v0 = *(const f32x4*)p;
    f32x4 v1 = *(const f32x4*)(p + 4);
#pragma unroll
    for (int j = 0; j < 4; ++j) {
        __bf16 h0 = (__bf16)v0[j];
        hi[j] = h0;
        lo[j] = (__bf16)(v0[j] - (float)h0);
        __bf16 h1 = (__bf16)v1[j];
        hi[4 + j] = h1;
        lo[4 + j] = (__bf16)(v1[j] - (float)h1);
    }
}

#define MFMA(a, b, c) __builtin_amdgcn_mfma_f32_16x16x32_bf16(a, b, c, 0, 0, 0)

// ---------------- layer GEMM via MFMA: a <- a @ ((1-beta)I + beta*W), in-place, + BN stats ----------------
// A is bf16 (already quantized) -> 2 MFMAs per tile (A*Whi + A*Wlo keeps weight precision ~fp32)
__global__ __launch_bounds__(256) void k_gemm_mfma(const __bf16* __restrict__ A, __bf16* __restrict__ Aout,
                                                   const float* __restrict__ W, float beta,
                                                   float* __restrict__ stats) {
    __shared__ __bf16 Bt[2][DH * 136];  // [hi/lo][col j][k], k-stride 1, col-stride 136
    __shared__ float red[2][4][DH];
    int tid = threadIdx.x;
    float ob = 1.0f - beta;
    for (int i = tid; i < DH * DH; i += 256) {
        int k = i >> 7, j = i & 127;
        float v = beta * W[i] + ((k == j) ? ob : 0.f);
        __bf16 hv = (__bf16)v;
        Bt[0][j * 136 + k] = hv;
        Bt[1][j * 136 + k] = (__bf16)(v - (float)hv);
    }
    __syncthreads();

    int wave = tid >> 6, lane = tid & 63;
    int n = lane & 15, quad = lane >> 4;
    int r0 = blockIdx.x * 64 + wave * 16;
    int arow = r0 + n;
    if (arow > NN - 1) arow = NN - 1;
    const __bf16* pa = A + (size_t)arow * DH + quad * 8;

    f32x4 acc[8];
#pragma unroll
    for (int t = 0; t < 8; ++t) acc[t] = (f32x4){0.f, 0.f, 0.f, 0.f};

#pragma unroll
    for (int ks = 0; ks < 4; ++ks) {
        bf16x8 av = *(const bf16x8*)(pa + ks * 32);
        int kb = ks * 32 + quad * 8;
#pragma unroll
        for (int t = 0; t < 8; ++t) {
            bf16x8 bh = *(const bf16x8*)&Bt[0][(t * 16 + n) * 136 + kb];
            bf16x8 bl = *(const bf16x8*)&Bt[1][(t * 16 + n) * 136 + kb];
            acc[t] = MFMA(av, bh, acc[t]);
            acc[t] = MFMA(av, bl, acc[t]);
        }
    }

    // epilogue: store bf16 + exact BN stats (fp32 accs; shfl across quads, LDS across waves, atomics)
#pragma unroll
    for (int t = 0; t < 8; ++t) {
        float s = 0.f, q = 0.f;
#pragma unroll
        for (int r = 0; r < 4; ++r) {
            int row = r0 + quad * 4 + r;
            float v = acc[t][r];
            if (row < NN) {
                Aout[(size_t)row * DH + t * 16 + n] = (__bf16)v;
                s += v;
                q += v * v;
            }
        }
        s += __shfl_xor(s, 16); s += __shfl_xor(s, 32);
        q += __shfl_xor(q, 16); q += __shfl_xor(q, 32);
        if (quad == 0) {
            red[0][wave][t * 16 + n] = s;
            red[1][wave][t * 16 + n] = q;
        }
    }
    __syncthreads();
    {
        int which = tid >> 7, j = tid & 127;
        float tot = red[which][0][j] + red[which][1][j] + red[which][2][j] + red[which][3][j];
        atomicAdd(&stats[tid], tot);
    }
}

// ---------------- input GEMM via MFMA: x0 = relu(X @ Win + bin), fp32 in -> bf16 out ----------------
__global__ __launch_bounds__(256) void k_lin_in(const float* __restrict__ X, const float* __restrict__ Win,
                                                const float* __restrict__ bin, __bf16* __restrict__ x0) {
    __shared__ __bf16 Bt[2][DH * 136];
    int tid = threadIdx.x;
    for (int i = tid; i < DH * DH; i += 256) {
        int k = i >> 7, j = i & 127;
        float v = Win[i];
        __bf16 hv = (__bf16)v;
        Bt[0][j * 136 + k] = hv;
        Bt[1][j * 136 + k] = (__bf16)(v - (float)hv);
    }
    __syncthreads();

    int wave = tid >> 6, lane = tid & 63;
    int n = lane & 15, quad = lane >> 4;
    int r0 = blockIdx.x * 64 + wave * 16;
    int arow = r0 + n;
    if (arow > NN - 1) arow = NN - 1;
    const float* pa = X + (size_t)arow * DH + quad * 8;

    f32x4 acc[8];
#pragma unroll
    for (int t = 0; t < 8; ++t) acc[t] = (f32x4){0.f, 0.f, 0.f, 0.f};

#pragma unroll
    for (int ks = 0; ks < 4; ++ks) {
        bf16x8 ah, al;
        split8(pa + ks * 32, ah, al);
        int kb = ks * 32 + quad * 8;
#pragma unroll
        for (int t = 0; t < 8; ++t) {
            bf16x8 bh = *(const bf16x8*)&Bt[0][(t * 16 + n) * 136 + kb];
            bf16x8 bl = *(const bf16x8*)&Bt[1][(t * 16 + n) * 136 + kb];
            acc[t] = MFMA(ah, bh, acc[t]);
            acc[t] = MFMA(al, bh, acc[t]);
            acc[t] = MFMA(ah, bl, acc[t]);
        }
    }

#pragma unroll
    for (int t = 0; t < 8; ++t) {
        float bj = bin[t * 16 + n];
#pragma unroll
        for (int r = 0; r < 4; ++r) {
            int row = r0 + quad * 4 + r;
            if (row < NN) {
                float v = fmaxf(acc[t][r] + bj, 0.f);
                x0[(size_t)row * DH + t * 16 + n] = (__bf16)v;
            }
        }
    }
}

// ---------------- output GEMM via MFMA: out = h @ Wout + bout (40 cols -> 3 tiles of 16) ----------------
__global__ __launch_bounds__(256) void k_gemm_out(const __bf16* __restrict__ A, const float* __restrict__ Wout,
                                                  const float* __restrict__ bout, float* __restrict__ out) {
    __shared__ __bf16 Bt[2][48 * 136];
    int tid = threadIdx.x;
    for (int i = tid; i < DH * 64; i += 256) {
        int k = i >> 6, j = i & 63;
        if (j < 48) {
            float v = (j < 40) ? Wout[k * 40 + j] : 0.f;
            __bf16 hv = (__bf16)v;
            Bt[0][j * 136 + k] = hv;
            Bt[1][j * 136 + k] = (__bf16)(v - (float)hv);
        }
    }
    __syncthreads();

    int wave = tid >> 6, lane = tid & 63;
    int n = lane & 15, quad = lane >> 4;
    int r0 = blockIdx.x * 64 + wave * 16;
    int arow = r0 + n;
    if (arow > NN - 1) arow = NN - 1;
    const __bf16* pa = A + (size_t)arow * DH + quad * 8;

    f32x4 acc[3];
#pragma unroll
    for (int t = 0; t < 3; ++t) acc[t] = (f32x4){0.f, 0.f, 0.f, 0.f};

#pragma unroll
    for (int ks = 0; ks < 4; ++ks) {
        bf16x8 av = *(const bf16x8*)(pa + ks * 32);
        int kb = ks * 32 + quad * 8;
#pragma unroll
        for (int t = 0; t < 3; ++t) {
            bf16x8 bh = *(const bf16x8*)&Bt[0][(t * 16 + n) * 136 + kb];
            bf16x8 bl = *(const bf16x8*)&Bt[1][(t * 16 + n) * 136 + kb];
            acc[t] = MFMA(av, bh, acc[t]);
            acc[t] = MFMA(av, bl, acc[t]);
        }
    }

#pragma unroll
    for (int t = 0; t < 3; ++t) {
        int j = t * 16 + n;
        float bj = (j < 40) ? bout[j] : 0.f;
#pragma unroll
        for (int r = 0; r < 4; ++r) {
            int row = r0 + quad * 4 + r;
            if (row < NN && j < 40) out[(size_t)row * 40 + j] = acc[t][r] + bj;
        }
    }
}

// ---------------- fused BN-finalize + update: h_out = relu(a*sc + sh + h_in) ----------------
__global__ __launch_bounds__(256) void k_update(const __bf16* __restrict__ a, const __bf16* __restrict__ hin,
                                                __bf16* __restrict__ hout, const float* __restrict__ stats,
                                                const float* __restrict__ gamma, const float* __restrict__ bbeta) {
    int idx = blockIdx.x * 256 + threadIdx.x;  // bf16x8 units: NN*DH/8 = 1.6M
    int j0 = (idx & 15) * 8;
    bf16x8 av = ((const bf16x8*)a)[idx];
    bf16x8 hv = ((const bf16x8*)hin)[idx];
    bf16x8 o;
#pragma unroll
    for (int c = 0; c < 8; ++c) {
        int j = j0 + c;
        float s = stats[j], s2 = stats[128 + j];
        float mu = s * (1.0f / NN);
        float var = s2 * (1.0f / NN) - mu * mu;
        if (var < 0.f) var = 0.f;
        float sc = gamma[j] * rsqrtf(var + 1e-5f);
        float sh = bbeta[j] - mu * sc;
        float v = fmaxf(fmaf((float)av[c], sc, sh) + (float)hv[c], 0.f);
        o[c] = (__bf16)v;
    }
    ((bf16x8*)hout)[idx] = o;
}

extern "C" void kernel_launch(void* const* d_in, const int* in_sizes, int n_in,
                              void* d_out, int out_size, void* d_ws, size_t ws_size,
                              hipStream_t stream) {
    const float* x = (const float*)d_in[0];
    const float* ew = (const float*)d_in[1];
    const float* Win = (const float*)d_in[2];
    const float* bin = (const float*)d_in[3];
    const float* convW = (const float*)d_in[4];
    const float* gamma = (const float*)d_in[5];
    const float* bbeta = (const float*)d_in[6];
    const float* Wout = (const float*)d_in[7];
    const float* bout = (const float*)d_in[8];
    const int* erow = (const int*)d_in[9];
    const int* ecol = (const int*)d_in[10];
    float* out = (float*)d_out;

    char* wsp = (char*)d_ws;
    size_t off = 0;
    auto alloc = [&](size_t bytes) -> void* {
        void* p = wsp + off;
        off += (bytes + 255) & ~(size_t)255;
        return p;
    };
    __bf16* x0 = (__bf16*)alloc((size_t)NN * DH * 2);
    __bf16* h = (__bf16*)alloc((size_t)NN * DH * 2);
    __bf16* a = (__bf16*)alloc((size_t)NN * DH * 2);
    int* rp = (int*)alloc((NN + 1) * 4);
    int* cnt = (int*)alloc(NN * 4);
    int* fil = (int*)alloc(NN * 4);
    int2* ep = (int2*)alloc((size_t)EE * 8);
    int* part = (int*)alloc(256 * 4);
    float* stats = (float*)alloc(NL * 256 * 4);

    hipMemsetAsync(cnt, 0, NN * 4, stream);
    hipMemsetAsync(fil, 0, NN * 4, stream);
    hipMemsetAsync(stats, 0, NL * 256 * 4, stream);

    k_hist<<<3125, 256, 0, stream>>>(erow, cnt);
    k_scan1<<<196, 512, 0, stream>>>(cnt, rp, part);
    k_scan2<<<1, 256, 0, stream>>>(part, 196);
    k_scan3<<<196, 512, 0, stream>>>(rp, part);
    k_fill<<<3125, 256, 0, stream>>>(erow, ecol, ew, rp, fil, ep);

    k_lin_in<<<1563, 256, 0, stream>>>(x, Win, bin, x0);

    for (int l = 0; l < NL; ++l) {
        float beta = logf(0.5f / (float)(l + 1) + 1.0f);
        const __bf16* hin = (l == 0) ? x0 : h;
        k_spmm<<<25000, 256, 0, stream>>>(hin, x0, rp, ep, a);
        k_gemm_mfma<<<1563, 256, 0, stream>>>(a, a, convW + (size_t)l * DH * DH, beta, stats + l * 256);
        k_update<<<6250, 256, 0, stream>>>(a, hin, h, stats + l * 256, gamma + l * DH, bbeta + l * DH);
    }
    k_gemm_out<<<1563, 256, 0, stream>>>(h, Wout, bout, out);
}

// Round 4
// 2152.757 us; speedup vs baseline: 1.7197x; 1.0284x over previous
//
#include <hip/hip_runtime.h>
#include <math.h>

#define NN 100000
#define EE 800000
#define DH 128
#define NL 16

typedef __bf16 bf16x8 __attribute__((ext_vector_type(8)));
typedef __bf16 bf16x2 __attribute__((ext_vector_type(2)));
typedef float f32x4 __attribute__((ext_vector_type(4)));

// ---------------- CSR build ----------------
__global__ void k_hist(const int* __restrict__ row, int* __restrict__ cnt) {
    int e = blockIdx.x * 256 + threadIdx.x;
    if (e < EE) atomicAdd(&cnt[row[e]], 1);
}

__global__ void k_scan1(const int* __restrict__ cnt, int* __restrict__ rp, int* __restrict__ part) {
    __shared__ int buf[512];
    int tid = threadIdx.x;
    int i = blockIdx.x * 512 + tid;
    int v = (i < NN) ? cnt[i] : 0;
    buf[tid] = v;
    __syncthreads();
    for (int off = 1; off < 512; off <<= 1) {
        int x = (tid >= off) ? buf[tid - off] : 0;
        __syncthreads();
        buf[tid] += x;
        __syncthreads();
    }
    if (i < NN) rp[i] = buf[tid] - v;
    if (tid == 511) part[blockIdx.x] = buf[511];
}

__global__ void k_scan2(int* __restrict__ part, int nparts) {
    __shared__ int buf[256];
    int tid = threadIdx.x;
    int v = (tid < nparts) ? part[tid] : 0;
    buf[tid] = v;
    __syncthreads();
    for (int off = 1; off < 256; off <<= 1) {
        int x = (tid >= off) ? buf[tid - off] : 0;
        __syncthreads();
        buf[tid] += x;
        __syncthreads();
    }
    if (tid < nparts) part[tid] = buf[tid] - v;
}

__global__ void k_scan3(int* __restrict__ rp, const int* __restrict__ part) {
    int i = blockIdx.x * 512 + threadIdx.x;
    if (i < NN) rp[i] += part[blockIdx.x];
    if (i == 0) rp[NN] = EE;
}

__global__ void k_fill(const int* __restrict__ row, const int* __restrict__ col,
                       const float* __restrict__ w, const int* __restrict__ rp,
                       int* __restrict__ fil, int2* __restrict__ ep) {
    int e = blockIdx.x * 256 + threadIdx.x;
    if (e >= EE) return;
    int r = row[e];
    int pos = rp[r] + atomicAdd(&fil[r], 1);
    ep[pos] = make_int2(col[e], __float_as_int(w[e]));
}

// ---------------- weight prep: split hi/lo bf16 + swizzle to MFMA fragment order ----------------
// dest layout: frag[t][ks][lane][e] = M[k][j], j = t*16 + (lane&15), k = ks*32 + (lane>>4)*8 + e
// block l < NL: M = (1-beta)I + beta*convW[l];  block l == NL: M = Win
__global__ void k_prep_w(const float* __restrict__ convW, const float* __restrict__ Win,
                         __bf16* __restrict__ Bhi, __bf16* __restrict__ Blo) {
    int l = blockIdx.x;
    const float* W;
    float beta, ob;
    if (l < NL) {
        beta = logf(0.5f / (float)(l + 1) + 1.0f);
        ob = 1.0f - beta;
        W = convW + (size_t)l * DH * DH;
    } else {
        beta = 1.0f;
        ob = 0.0f;
        W = Win;
    }
    __bf16* bh = Bhi + (size_t)l * DH * DH;
    __bf16* bl = Blo + (size_t)l * DH * DH;
    for (int i = threadIdx.x; i < DH * DH; i += 256) {
        int k = i >> 7, j = i & 127;
        float v = beta * W[i] + ((k == j) ? ob : 0.f);
        __bf16 hv = (__bf16)v;
        int t = j >> 4, n = j & 15, ks = k >> 5, quad = (k >> 3) & 3, e = k & 7;
        int off = ((t * 4 + ks) * 64 + quad * 16 + n) * 8 + e;
        bh[off] = hv;
        bl[off] = (__bf16)(v - (float)hv);
    }
}

// Wout prep: 40 cols padded to 48 (3 tiles of 16)
__global__ void k_prep_out(const float* __restrict__ Wout, __bf16* __restrict__ Bhi, __bf16* __restrict__ Blo) {
    for (int i = threadIdx.x; i < DH * 48; i += 256) {
        int k = i / 48, j = i % 48;
        float v = (j < 40) ? Wout[k * 40 + j] : 0.f;
        __bf16 hv = (__bf16)v;
        int t = j >> 4, n = j & 15, ks = k >> 5, quad = (k >> 3) & 3, e = k & 7;
        int off = ((t * 4 + ks) * 64 + quad * 16 + n) * 8 + e;
        Bhi[off] = hv;
        Blo[off] = (__bf16)(v - (float)hv);
    }
}

// ---------------- SpMM + mix: a = 0.9*(Adj@h) + 0.1*x0 ; bf16 activations ----------------
__global__ __launch_bounds__(256) void k_spmm(const __bf16* __restrict__ h, const __bf16* __restrict__ x0,
                                              const int* __restrict__ rp, const int2* __restrict__ ep,
                                              __bf16* __restrict__ a) {
    int node = blockIdx.x * 4 + (threadIdx.x >> 6);
    int lane = threadIdx.x & 63;
    int fo = lane * 2;
    float2 acc = make_float2(0.f, 0.f);
    int s = rp[node], e = rp[node + 1];
    int i = s;
    for (; i + 3 < e; i += 4) {
        int2 p0 = ep[i], p1 = ep[i + 1], p2 = ep[i + 2], p3 = ep[i + 3];
        bf16x2 v0 = *(const bf16x2*)&h[(size_t)p0.x * DH + fo];
        bf16x2 v1 = *(const bf16x2*)&h[(size_t)p1.x * DH + fo];
        bf16x2 v2 = *(const bf16x2*)&h[(size_t)p2.x * DH + fo];
        bf16x2 v3 = *(const bf16x2*)&h[(size_t)p3.x * DH + fo];
        float w0 = __int_as_float(p0.y), w1 = __int_as_float(p1.y);
        float w2 = __int_as_float(p2.y), w3 = __int_as_float(p3.y);
        acc.x = fmaf(w0, (float)v0[0], acc.x); acc.y = fmaf(w0, (float)v0[1], acc.y);
        acc.x = fmaf(w1, (float)v1[0], acc.x); acc.y = fmaf(w1, (float)v1[1], acc.y);
        acc.x = fmaf(w2, (float)v2[0], acc.x); acc.y = fmaf(w2, (float)v2[1], acc.y);
        acc.x = fmaf(w3, (float)v3[0], acc.x); acc.y = fmaf(w3, (float)v3[1], acc.y);
    }
    for (; i < e; ++i) {
        int2 p = ep[i];
        float w = __int_as_float(p.y);
        bf16x2 v = *(const bf16x2*)&h[(size_t)p.x * DH + fo];
        acc.x = fmaf(w, (float)v[0], acc.x);
        acc.y = fmaf(w, (float)v[1], acc.y);
    }
    bf16x2 xv = *(const bf16x2*)&x0[(size_t)node * DH + fo];
    bf16x2 o;
    o[0] = (__bf16)fmaf(0.9f, acc.x, 0.1f * (float)xv[0]);
    o[1] = (__bf16)fmaf(0.9f, acc.y, 0.1f * (float)xv[1]);
    *(bf16x2*)&a[(size_t)node * DH + fo] = o;
}

__device__ inline void split8(const float* p, bf16x8& hi, bf16x8& lo) {
    f32x4 v0 = *(const f32x4*)p;
    f32x4 v1 = *(const f32x4*)(p + 4);
#pragma unroll
    for (int j = 0; j < 4; ++j) {
        __bf16 h0 = (__bf16)v0[j];
        hi[j] = h0;
        lo[j] = (__bf16)(v0[j] - (float)h0);
        __bf16 h1 = (__bf16)v1[j];
        hi[4 + j] = h1;
        lo[4 + j] = (__bf16)(v1[j] - (float)h1);
    }
}

#define MFMA(a, b, c) __builtin_amdgcn_mfma_f32_16x16x32_bf16(a, b, c, 0, 0, 0)

// ---------------- layer GEMM via MFMA, B fragments direct from global (no LDS staging) ----------------
__global__ __launch_bounds__(256) void k_gemm_mfma(const __bf16* __restrict__ A, __bf16* __restrict__ Aout,
                                                   const __bf16* __restrict__ Bhi, const __bf16* __restrict__ Blo,
                                                   float* __restrict__ stats) {
    __shared__ float red[2][4][DH];
    int tid = threadIdx.x;
    int wave = tid >> 6, lane = tid & 63;
    int n = lane & 15, quad = lane >> 4;
    int r0 = blockIdx.x * 64 + wave * 16;
    int arow = r0 + n;
    if (arow > NN - 1) arow = NN - 1;
    const __bf16* pa = A + (size_t)arow * DH + quad * 8;

    f32x4 acc[8];
#pragma unroll
    for (int t = 0; t < 8; ++t) acc[t] = (f32x4){0.f, 0.f, 0.f, 0.f};

#pragma unroll
    for (int ks = 0; ks < 4; ++ks) {
        bf16x8 av = *(const bf16x8*)(pa + ks * 32);
#pragma unroll
        for (int t = 0; t < 8; ++t) {
            int base = ((t * 4 + ks) * 64 + lane) * 8;
            bf16x8 bh = *(const bf16x8*)&Bhi[base];
            bf16x8 bl = *(const bf16x8*)&Blo[base];
            acc[t] = MFMA(av, bh, acc[t]);
            acc[t] = MFMA(av, bl, acc[t]);
        }
    }

#pragma unroll
    for (int t = 0; t < 8; ++t) {
        float s = 0.f, q = 0.f;
#pragma unroll
        for (int r = 0; r < 4; ++r) {
            int row = r0 + quad * 4 + r;
            float v = acc[t][r];
            if (row < NN) {
                Aout[(size_t)row * DH + t * 16 + n] = (__bf16)v;
                s += v;
                q += v * v;
            }
        }
        s += __shfl_xor(s, 16); s += __shfl_xor(s, 32);
        q += __shfl_xor(q, 16); q += __shfl_xor(q, 32);
        if (quad == 0) {
            red[0][wave][t * 16 + n] = s;
            red[1][wave][t * 16 + n] = q;
        }
    }
    __syncthreads();
    {
        int which = tid >> 7, j = tid & 127;
        float tot = red[which][0][j] + red[which][1][j] + red[which][2][j] + red[which][3][j];
        atomicAdd(&stats[tid], tot);
    }
}

// ---------------- input GEMM: x0 = relu(X @ Win + bin), fp32 A split on the fly ----------------
__global__ __launch_bounds__(256) void k_lin_in(const float* __restrict__ X,
                                                const __bf16* __restrict__ Bhi, const __bf16* __restrict__ Blo,
                                                const float* __restrict__ bin, __bf16* __restrict__ x0) {
    int tid = threadIdx.x;
    int wave = tid >> 6, lane = tid & 63;
    int n = lane & 15, quad = lane >> 4;
    int r0 = blockIdx.x * 64 + wave * 16;
    int arow = r0 + n;
    if (arow > NN - 1) arow = NN - 1;
    const float* pa = X + (size_t)arow * DH + quad * 8;

    f32x4 acc[8];
#pragma unroll
    for (int t = 0; t < 8; ++t) acc[t] = (f32x4){0.f, 0.f, 0.f, 0.f};

#pragma unroll
    for (int ks = 0; ks < 4; ++ks) {
        bf16x8 ah, al;
        split8(pa + ks * 32, ah, al);
#pragma unroll
        for (int t = 0; t < 8; ++t) {
            int base = ((t * 4 + ks) * 64 + lane) * 8;
            bf16x8 bh = *(const bf16x8*)&Bhi[base];
            bf16x8 bl = *(const bf16x8*)&Blo[base];
            acc[t] = MFMA(ah, bh, acc[t]);
            acc[t] = MFMA(al, bh, acc[t]);
            acc[t] = MFMA(ah, bl, acc[t]);
        }
    }

#pragma unroll
    for (int t = 0; t < 8; ++t) {
        float bj = bin[t * 16 + n];
#pragma unroll
        for (int r = 0; r < 4; ++r) {
            int row = r0 + quad * 4 + r;
            if (row < NN) {
                float v = fmaxf(acc[t][r] + bj, 0.f);
                x0[(size_t)row * DH + t * 16 + n] = (__bf16)v;
            }
        }
    }
}

// ---------------- output GEMM: out = h @ Wout + bout (3 tiles of 16 cols) ----------------
__global__ __launch_bounds__(256) void k_gemm_out(const __bf16* __restrict__ A,
                                                  const __bf16* __restrict__ Bhi, const __bf16* __restrict__ Blo,
                                                  const float* __restrict__ bout, float* __restrict__ out) {
    int tid = threadIdx.x;
    int wave = tid >> 6, lane = tid & 63;
    int n = lane & 15, quad = lane >> 4;
    int r0 = blockIdx.x * 64 + wave * 16;
    int arow = r0 + n;
    if (arow > NN - 1) arow = NN - 1;
    const __bf16* pa = A + (size_t)arow * DH + quad * 8;

    f32x4 acc[3];
#pragma unroll
    for (int t = 0; t < 3; ++t) acc[t] = (f32x4){0.f, 0.f, 0.f, 0.f};

#pragma unroll
    for (int ks = 0; ks < 4; ++ks) {
        bf16x8 av = *(const bf16x8*)(pa + ks * 32);
#pragma unroll
        for (int t = 0; t < 3; ++t) {
            int base = ((t * 4 + ks) * 64 + lane) * 8;
            bf16x8 bh = *(const bf16x8*)&Bhi[base];
            bf16x8 bl = *(const bf16x8*)&Blo[base];
            acc[t] = MFMA(av, bh, acc[t]);
            acc[t] = MFMA(av, bl, acc[t]);
        }
    }

#pragma unroll
    for (int t = 0; t < 3; ++t) {
        int j = t * 16 + n;
        float bj = (j < 40) ? bout[j] : 0.f;
#pragma unroll
        for (int r = 0; r < 4; ++r) {
            int row = r0 + quad * 4 + r;
            if (row < NN && j < 40) out[(size_t)row * 40 + j] = acc[t][r] + bj;
        }
    }
}

// ---------------- fused BN-finalize + update: h_out = relu(a*sc + sh + h_in) ----------------
__global__ __launch_bounds__(256) void k_update(const __bf16* __restrict__ a, const __bf16* __restrict__ hin,
                                                __bf16* __restrict__ hout, const float* __restrict__ stats,
                                                const float* __restrict__ gamma, const float* __restrict__ bbeta) {
    int idx = blockIdx.x * 256 + threadIdx.x;
    int j0 = (idx & 15) * 8;
    bf16x8 av = ((const bf16x8*)a)[idx];
    bf16x8 hv = ((const bf16x8*)hin)[idx];
    bf16x8 o;
#pragma unroll
    for (int c = 0; c < 8; ++c) {
        int j = j0 + c;
        float s = stats[j], s2 = stats[128 + j];
        float mu = s * (1.0f / NN);
        float var = s2 * (1.0f / NN) - mu * mu;
        if (var < 0.f) var = 0.f;
        float sc = gamma[j] * rsqrtf(var + 1e-5f);
        float sh = bbeta[j] - mu * sc;
        float v = fmaxf(fmaf((float)av[c], sc, sh) + (float)hv[c], 0.f);
        o[c] = (__bf16)v;
    }
    ((bf16x8*)hout)[idx] = o;
}

extern "C" void kernel_launch(void* const* d_in, const int* in_sizes, int n_in,
                              void* d_out, int out_size, void* d_ws, size_t ws_size,
                              hipStream_t stream) {
    const float* x = (const float*)d_in[0];
    const float* ew = (const float*)d_in[1];
    const float* Win = (const float*)d_in[2];
    const float* bin = (const float*)d_in[3];
    const float* convW = (const float*)d_in[4];
    const float* gamma = (const float*)d_in[5];
    const float* bbeta = (const float*)d_in[6];
    const float* Wout = (const float*)d_in[7];
    const float* bout = (const float*)d_in[8];
    const int* erow = (const int*)d_in[9];
    const int* ecol = (const int*)d_in[10];
    float* out = (float*)d_out;

    char* wsp = (char*)d_ws;
    size_t off = 0;
    auto alloc = [&](size_t bytes) -> void* {
        void* p = wsp + off;
        off += (bytes + 255) & ~(size_t)255;
        return p;
    };
    __bf16* x0 = (__bf16*)alloc((size_t)NN * DH * 2);
    __bf16* h = (__bf16*)alloc((size_t)NN * DH * 2);
    __bf16* a = (__bf16*)alloc((size_t)NN * DH * 2);
    int* rp = (int*)alloc((NN + 1) * 4);
    int* cnt = (int*)alloc(NN * 4);
    int* fil = (int*)alloc(NN * 4);
    int2* ep = (int2*)alloc((size_t)EE * 8);
    int* part = (int*)alloc(256 * 4);
    float* stats = (float*)alloc(NL * 256 * 4);
    __bf16* Bhi = (__bf16*)alloc((size_t)(NL + 1) * DH * DH * 2);  // layers + Win
    __bf16* Blo = (__bf16*)alloc((size_t)(NL + 1) * DH * DH * 2);
    __bf16* Bohi = (__bf16*)alloc((size_t)DH * 48 * 2);
    __bf16* Bolo = (__bf16*)alloc((size_t)DH * 48 * 2);

    hipMemsetAsync(cnt, 0, NN * 4, stream);
    hipMemsetAsync(fil, 0, NN * 4, stream);
    hipMemsetAsync(stats, 0, NL * 256 * 4, stream);

    k_hist<<<3125, 256, 0, stream>>>(erow, cnt);
    k_scan1<<<196, 512, 0, stream>>>(cnt, rp, part);
    k_scan2<<<1, 256, 0, stream>>>(part, 196);
    k_scan3<<<196, 512, 0, stream>>>(rp, part);
    k_fill<<<3125, 256, 0, stream>>>(erow, ecol, ew, rp, fil, ep);

    k_prep_w<<<NL + 1, 256, 0, stream>>>(convW, Win, Bhi, Blo);
    k_prep_out<<<1, 256, 0, stream>>>(Wout, Bohi, Bolo);

    k_lin_in<<<1563, 256, 0, stream>>>(x, Bhi + (size_t)NL * DH * DH, Blo + (size_t)NL * DH * DH, bin, x0);

    for (int l = 0; l < NL; ++l) {
        const __bf16* hin = (l == 0) ? x0 : h;
        k_spmm<<<25000, 256, 0, stream>>>(hin, x0, rp, ep, a);
        k_gemm_mfma<<<1563, 256, 0, stream>>>(a, a, Bhi + (size_t)l * DH * DH, Blo + (size_t)l * DH * DH,
                                              stats + l * 256);
        k_update<<<6250, 256, 0, stream>>>(a, hin, h, stats + l * 256, gamma + l * DH, bbeta + l * DH);
    }
    k_gemm_out<<<1563, 256, 0, stream>>>(h, Bohi, Bolo, bout, out);
}

// Round 5
// 1787.741 us; speedup vs baseline: 2.0708x; 1.2042x over previous
//
#include <hip/hip_runtime.h>
#include <math.h>

#define NN 100000
#define EE 800000
#define DH 128
#define NL 16
#define GEMM_GRID 1563

typedef __bf16 bf16x8 __attribute__((ext_vector_type(8)));
typedef __bf16 bf16x2 __attribute__((ext_vector_type(2)));
typedef float f32x4 __attribute__((ext_vector_type(4)));

// ---------------- CSR build ----------------
__global__ void k_hist(const int* __restrict__ row, int* __restrict__ cnt) {
    int e = blockIdx.x * 256 + threadIdx.x;
    if (e < EE) atomicAdd(&cnt[row[e]], 1);
}

__global__ void k_scan1(const int* __restrict__ cnt, int* __restrict__ rp, int* __restrict__ part) {
    __shared__ int buf[512];
    int tid = threadIdx.x;
    int i = blockIdx.x * 512 + tid;
    int v = (i < NN) ? cnt[i] : 0;
    buf[tid] = v;
    __syncthreads();
    for (int off = 1; off < 512; off <<= 1) {
        int x = (tid >= off) ? buf[tid - off] : 0;
        __syncthreads();
        buf[tid] += x;
        __syncthreads();
    }
    if (i < NN) rp[i] = buf[tid] - v;
    if (tid == 511) part[blockIdx.x] = buf[511];
}

__global__ void k_scan2(int* __restrict__ part, int nparts) {
    __shared__ int buf[256];
    int tid = threadIdx.x;
    int v = (tid < nparts) ? part[tid] : 0;
    buf[tid] = v;
    __syncthreads();
    for (int off = 1; off < 256; off <<= 1) {
        int x = (tid >= off) ? buf[tid - off] : 0;
        __syncthreads();
        buf[tid] += x;
        __syncthreads();
    }
    if (tid < nparts) part[tid] = buf[tid] - v;
}

__global__ void k_scan3(int* __restrict__ rp, const int* __restrict__ part) {
    int i = blockIdx.x * 512 + threadIdx.x;
    if (i < NN) rp[i] += part[blockIdx.x];
    if (i == 0) rp[NN] = EE;
}

__global__ void k_fill(const int* __restrict__ row, const int* __restrict__ col,
                       const float* __restrict__ w, const int* __restrict__ rp,
                       int* __restrict__ fil, int2* __restrict__ ep) {
    int e = blockIdx.x * 256 + threadIdx.x;
    if (e >= EE) return;
    int r = row[e];
    int pos = rp[r] + atomicAdd(&fil[r], 1);
    ep[pos] = make_int2(col[e], __float_as_int(w[e]));
}

// ---------------- weight prep: split hi/lo bf16 + swizzle to MFMA fragment order ----------------
// frag[t][ks][lane][e] = M[k][j], j = t*16 + (lane&15), k = ks*32 + (lane>>4)*8 + e
__global__ void k_prep_w(const float* __restrict__ convW, const float* __restrict__ Win,
                         __bf16* __restrict__ Bhi, __bf16* __restrict__ Blo) {
    int l = blockIdx.x;
    const float* W;
    float beta, ob;
    if (l < NL) {
        beta = logf(0.5f / (float)(l + 1) + 1.0f);
        ob = 1.0f - beta;
        W = convW + (size_t)l * DH * DH;
    } else {
        beta = 1.0f;
        ob = 0.0f;
        W = Win;
    }
    __bf16* bh = Bhi + (size_t)l * DH * DH;
    __bf16* bl = Blo + (size_t)l * DH * DH;
    for (int i = threadIdx.x; i < DH * DH; i += 256) {
        int k = i >> 7, j = i & 127;
        float v = beta * W[i] + ((k == j) ? ob : 0.f);
        __bf16 hv = (__bf16)v;
        int t = j >> 4, n = j & 15, ks = k >> 5, quad = (k >> 3) & 3, e = k & 7;
        int off = ((t * 4 + ks) * 64 + quad * 16 + n) * 8 + e;
        bh[off] = hv;
        bl[off] = (__bf16)(v - (float)hv);
    }
}

__global__ void k_prep_out(const float* __restrict__ Wout, __bf16* __restrict__ Bhi, __bf16* __restrict__ Blo) {
    for (int i = threadIdx.x; i < DH * 48; i += 256) {
        int k = i / 48, j = i % 48;
        float v = (j < 40) ? Wout[k * 40 + j] : 0.f;
        __bf16 hv = (__bf16)v;
        int t = j >> 4, n = j & 15, ks = k >> 5, quad = (k >> 3) & 3, e = k & 7;
        int off = ((t * 4 + ks) * 64 + quad * 16 + n) * 8 + e;
        Bhi[off] = hv;
        Blo[off] = (__bf16)(v - (float)hv);
    }
}

// ---------------- SpMM + mix: a = 0.9*(Adj@h) + 0.1*x0 ; bf16 activations ----------------
__global__ __launch_bounds__(256) void k_spmm(const __bf16* __restrict__ h, const __bf16* __restrict__ x0,
                                              const int* __restrict__ rp, const int2* __restrict__ ep,
                                              __bf16* __restrict__ a) {
    int node = blockIdx.x * 4 + (threadIdx.x >> 6);
    int lane = threadIdx.x & 63;
    int fo = lane * 2;
    float2 acc = make_float2(0.f, 0.f);
    int s = rp[node], e = rp[node + 1];
    int i = s;
    for (; i + 3 < e; i += 4) {
        int2 p0 = ep[i], p1 = ep[i + 1], p2 = ep[i + 2], p3 = ep[i + 3];
        bf16x2 v0 = *(const bf16x2*)&h[(size_t)p0.x * DH + fo];
        bf16x2 v1 = *(const bf16x2*)&h[(size_t)p1.x * DH + fo];
        bf16x2 v2 = *(const bf16x2*)&h[(size_t)p2.x * DH + fo];
        bf16x2 v3 = *(const bf16x2*)&h[(size_t)p3.x * DH + fo];
        float w0 = __int_as_float(p0.y), w1 = __int_as_float(p1.y);
        float w2 = __int_as_float(p2.y), w3 = __int_as_float(p3.y);
        acc.x = fmaf(w0, (float)v0[0], acc.x); acc.y = fmaf(w0, (float)v0[1], acc.y);
        acc.x = fmaf(w1, (float)v1[0], acc.x); acc.y = fmaf(w1, (float)v1[1], acc.y);
        acc.x = fmaf(w2, (float)v2[0], acc.x); acc.y = fmaf(w2, (float)v2[1], acc.y);
        acc.x = fmaf(w3, (float)v3[0], acc.x); acc.y = fmaf(w3, (float)v3[1], acc.y);
    }
    for (; i < e; ++i) {
        int2 p = ep[i];
        float w = __int_as_float(p.y);
        bf16x2 v = *(const bf16x2*)&h[(size_t)p.x * DH + fo];
        acc.x = fmaf(w, (float)v[0], acc.x);
        acc.y = fmaf(w, (float)v[1], acc.y);
    }
    bf16x2 xv = *(const bf16x2*)&x0[(size_t)node * DH + fo];
    bf16x2 o;
    o[0] = (__bf16)fmaf(0.9f, acc.x, 0.1f * (float)xv[0]);
    o[1] = (__bf16)fmaf(0.9f, acc.y, 0.1f * (float)xv[1]);
    *(bf16x2*)&a[(size_t)node * DH + fo] = o;
}

__device__ inline void split8(const float* p, bf16x8& hi, bf16x8& lo) {
    f32x4 v0 = *(const f32x4*)p;
    f32x4 v1 = *(const f32x4*)(p + 4);
#pragma unroll
    for (int j = 0; j < 4; ++j) {
        __bf16 h0 = (__bf16)v0[j];
        hi[j] = h0;
        lo[j] = (__bf16)(v0[j] - (float)h0);
        __bf16 h1 = (__bf16)v1[j];
        hi[4 + j] = h1;
        lo[4 + j] = (__bf16)(v1[j] - (float)h1);
    }
}

#define MFMA(a, b, c) __builtin_amdgcn_mfma_f32_16x16x32_bf16(a, b, c, 0, 0, 0)

// ---------------- layer GEMM: B fragments staged in LDS; stats -> per-block partials (no atomics) ----------------
__global__ __launch_bounds__(256) void k_gemm_mfma(const __bf16* __restrict__ A, __bf16* __restrict__ Aout,
                                                   const __bf16* __restrict__ Bhi, const __bf16* __restrict__ Blo,
                                                   float* __restrict__ partials) {
    __shared__ __bf16 Bs[2 * DH * DH];  // [hi|lo] in MFMA fragment order -> stride-1 conflict-free b128 reads
    __shared__ float red[2][4][DH];
    int tid = threadIdx.x;
    {
        const f32x4* sh = (const f32x4*)Bhi;
        const f32x4* sl = (const f32x4*)Blo;
        f32x4* dh = (f32x4*)Bs;
        f32x4* dl = (f32x4*)(Bs + DH * DH);
#pragma unroll
        for (int i = 0; i < 8; ++i) {
            dh[tid + i * 256] = sh[tid + i * 256];
            dl[tid + i * 256] = sl[tid + i * 256];
        }
    }
    __syncthreads();

    int wave = tid >> 6, lane = tid & 63;
    int n = lane & 15, quad = lane >> 4;
    int r0 = blockIdx.x * 64 + wave * 16;
    int arow = r0 + n;
    if (arow > NN - 1) arow = NN - 1;
    const __bf16* pa = A + (size_t)arow * DH + quad * 8;

    f32x4 acc[8];
#pragma unroll
    for (int t = 0; t < 8; ++t) acc[t] = (f32x4){0.f, 0.f, 0.f, 0.f};

#pragma unroll
    for (int ks = 0; ks < 4; ++ks) {
        bf16x8 av = *(const bf16x8*)(pa + ks * 32);
#pragma unroll
        for (int t = 0; t < 8; ++t) {
            int base = ((t * 4 + ks) * 64 + lane) * 8;
            bf16x8 bh = *(const bf16x8*)&Bs[base];
            bf16x8 bl = *(const bf16x8*)&Bs[DH * DH + base];
            acc[t] = MFMA(av, bh, acc[t]);
            acc[t] = MFMA(av, bl, acc[t]);
        }
    }

#pragma unroll
    for (int t = 0; t < 8; ++t) {
        float s = 0.f, q = 0.f;
#pragma unroll
        for (int r = 0; r < 4; ++r) {
            int row = r0 + quad * 4 + r;
            float v = acc[t][r];
            if (row < NN) {
                Aout[(size_t)row * DH + t * 16 + n] = (__bf16)v;
                s += v;
                q += v * v;
            }
        }
        s += __shfl_xor(s, 16); s += __shfl_xor(s, 32);
        q += __shfl_xor(q, 16); q += __shfl_xor(q, 32);
        if (quad == 0) {
            red[0][wave][t * 16 + n] = s;
            red[1][wave][t * 16 + n] = q;
        }
    }
    __syncthreads();
    {
        int which = tid >> 7, j = tid & 127;
        float tot = red[which][0][j] + red[which][1][j] + red[which][2][j] + red[which][3][j];
        partials[(size_t)blockIdx.x * 256 + tid] = tot;  // coalesced, no atomics
    }
}

// ---------------- stats reduce: partials[GEMM_GRID][256] -> stats[256] ----------------
__global__ void k_stats(const float* __restrict__ partials, float* __restrict__ stats) {
    float s = 0.f;
    for (int b = blockIdx.x; b < GEMM_GRID; b += 64)
        s += partials[(size_t)b * 256 + threadIdx.x];
    atomicAdd(&stats[threadIdx.x], s);  // only 64 adds per address
}

// ---------------- input GEMM: x0 = relu(X @ Win + bin), fp32 A split on the fly, B in LDS ----------------
__global__ __launch_bounds__(256) void k_lin_in(const float* __restrict__ X,
                                                const __bf16* __restrict__ Bhi, const __bf16* __restrict__ Blo,
                                                const float* __restrict__ bin, __bf16* __restrict__ x0) {
    __shared__ __bf16 Bs[2 * DH * DH];
    int tid = threadIdx.x;
    {
        const f32x4* sh = (const f32x4*)Bhi;
        const f32x4* sl = (const f32x4*)Blo;
        f32x4* dh = (f32x4*)Bs;
        f32x4* dl = (f32x4*)(Bs + DH * DH);
#pragma unroll
        for (int i = 0; i < 8; ++i) {
            dh[tid + i * 256] = sh[tid + i * 256];
            dl[tid + i * 256] = sl[tid + i * 256];
        }
    }
    __syncthreads();

    int wave = tid >> 6, lane = tid & 63;
    int n = lane & 15, quad = lane >> 4;
    int r0 = blockIdx.x * 64 + wave * 16;
    int arow = r0 + n;
    if (arow > NN - 1) arow = NN - 1;
    const float* pa = X + (size_t)arow * DH + quad * 8;

    f32x4 acc[8];
#pragma unroll
    for (int t = 0; t < 8; ++t) acc[t] = (f32x4){0.f, 0.f, 0.f, 0.f};

#pragma unroll
    for (int ks = 0; ks < 4; ++ks) {
        bf16x8 ah, al;
        split8(pa + ks * 32, ah, al);
#pragma unroll
        for (int t = 0; t < 8; ++t) {
            int base = ((t * 4 + ks) * 64 + lane) * 8;
            bf16x8 bh = *(const bf16x8*)&Bs[base];
            bf16x8 bl = *(const bf16x8*)&Bs[DH * DH + base];
            acc[t] = MFMA(ah, bh, acc[t]);
            acc[t] = MFMA(al, bh, acc[t]);
            acc[t] = MFMA(ah, bl, acc[t]);
        }
    }

#pragma unroll
    for (int t = 0; t < 8; ++t) {
        float bj = bin[t * 16 + n];
#pragma unroll
        for (int r = 0; r < 4; ++r) {
            int row = r0 + quad * 4 + r;
            if (row < NN) {
                float v = fmaxf(acc[t][r] + bj, 0.f);
                x0[(size_t)row * DH + t * 16 + n] = (__bf16)v;
            }
        }
    }
}

// ---------------- output GEMM: out = h @ Wout + bout (3 tiles of 16 cols), B in LDS ----------------
__global__ __launch_bounds__(256) void k_gemm_out(const __bf16* __restrict__ A,
                                                  const __bf16* __restrict__ Bhi, const __bf16* __restrict__ Blo,
                                                  const float* __restrict__ bout, float* __restrict__ out) {
    __shared__ __bf16 Bs[2 * 48 * DH];  // 24 KB
    int tid = threadIdx.x;
    {
        const f32x4* sh = (const f32x4*)Bhi;
        const f32x4* sl = (const f32x4*)Blo;
        f32x4* dh = (f32x4*)Bs;
        f32x4* dl = (f32x4*)(Bs + 48 * DH);
#pragma unroll
        for (int i = 0; i < 3; ++i) {
            dh[tid + i * 256] = sh[tid + i * 256];
            dl[tid + i * 256] = sl[tid + i * 256];
        }
    }
    __syncthreads();

    int wave = tid >> 6, lane = tid & 63;
    int n = lane & 15, quad = lane >> 4;
    int r0 = blockIdx.x * 64 + wave * 16;
    int arow = r0 + n;
    if (arow > NN - 1) arow = NN - 1;
    const __bf16* pa = A + (size_t)arow * DH + quad * 8;

    f32x4 acc[3];
#pragma unroll
    for (int t = 0; t < 3; ++t) acc[t] = (f32x4){0.f, 0.f, 0.f, 0.f};

#pragma unroll
    for (int ks = 0; ks < 4; ++ks) {
        bf16x8 av = *(const bf16x8*)(pa + ks * 32);
#pragma unroll
        for (int t = 0; t < 3; ++t) {
            int base = ((t * 4 + ks) * 64 + lane) * 8;
            bf16x8 bh = *(const bf16x8*)&Bs[base];
            bf16x8 bl = *(const bf16x8*)&Bs[48 * DH + base];
            acc[t] = MFMA(av, bh, acc[t]);
            acc[t] = MFMA(av, bl, acc[t]);
        }
    }

#pragma unroll
    for (int t = 0; t < 3; ++t) {
        int j = t * 16 + n;
        float bj = (j < 40) ? bout[j] : 0.f;
#pragma unroll
        for (int r = 0; r < 4; ++r) {
            int row = r0 + quad * 4 + r;
            if (row < NN && j < 40) out[(size_t)row * 40 + j] = acc[t][r] + bj;
        }
    }
}

// ---------------- fused BN-finalize + update: h_out = relu(a*sc + sh + h_in) ----------------
__global__ __launch_bounds__(256) void k_update(const __bf16* __restrict__ a, const __bf16* __restrict__ hin,
                                                __bf16* __restrict__ hout, const float* __restrict__ stats,
                                                const float* __restrict__ gamma, const float* __restrict__ bbeta) {
    int idx = blockIdx.x * 256 + threadIdx.x;
    int j0 = (idx & 15) * 8;
    bf16x8 av = ((const bf16x8*)a)[idx];
    bf16x8 hv = ((const bf16x8*)hin)[idx];
    bf16x8 o;
#pragma unroll
    for (int c = 0; c < 8; ++c) {
        int j = j0 + c;
        float s = stats[j], s2 = stats[128 + j];
        float mu = s * (1.0f / NN);
        float var = s2 * (1.0f / NN) - mu * mu;
        if (var < 0.f) var = 0.f;
        float sc = gamma[j] * rsqrtf(var + 1e-5f);
        float sh = bbeta[j] - mu * sc;
        float v = fmaxf(fmaf((float)av[c], sc, sh) + (float)hv[c], 0.f);
        o[c] = (__bf16)v;
    }
    ((bf16x8*)hout)[idx] = o;
}

extern "C" void kernel_launch(void* const* d_in, const int* in_sizes, int n_in,
                              void* d_out, int out_size, void* d_ws, size_t ws_size,
                              hipStream_t stream) {
    const float* x = (const float*)d_in[0];
    const float* ew = (const float*)d_in[1];
    const float* Win = (const float*)d_in[2];
    const float* bin = (const float*)d_in[3];
    const float* convW = (const float*)d_in[4];
    const float* gamma = (const float*)d_in[5];
    const float* bbeta = (const float*)d_in[6];
    const float* Wout = (const float*)d_in[7];
    const float* bout = (const float*)d_in[8];
    const int* erow = (const int*)d_in[9];
    const int* ecol = (const int*)d_in[10];
    float* out = (float*)d_out;

    char* wsp = (char*)d_ws;
    size_t off = 0;
    auto alloc = [&](size_t bytes) -> void* {
        void* p = wsp + off;
        off += (bytes + 255) & ~(size_t)255;
        return p;
    };
    __bf16* x0 = (__bf16*)alloc((size_t)NN * DH * 2);
    __bf16* h = (__bf16*)alloc((size_t)NN * DH * 2);
    __bf16* a = (__bf16*)alloc((size_t)NN * DH * 2);
    int* rp = (int*)alloc((NN + 1) * 4);
    int* cnt = (int*)alloc(NN * 4);
    int* fil = (int*)alloc(NN * 4);
    int2* ep = (int2*)alloc((size_t)EE * 8);
    int* part = (int*)alloc(256 * 4);
    float* stats = (float*)alloc(NL * 256 * 4);
    float* partials = (float*)alloc((size_t)GEMM_GRID * 256 * 4);
    __bf16* Bhi = (__bf16*)alloc((size_t)(NL + 1) * DH * DH * 2);
    __bf16* Blo = (__bf16*)alloc((size_t)(NL + 1) * DH * DH * 2);
    __bf16* Bohi = (__bf16*)alloc((size_t)DH * 48 * 2);
    __bf16* Bolo = (__bf16*)alloc((size_t)DH * 48 * 2);

    hipMemsetAsync(cnt, 0, NN * 4, stream);
    hipMemsetAsync(fil, 0, NN * 4, stream);
    hipMemsetAsync(stats, 0, NL * 256 * 4, stream);

    k_hist<<<3125, 256, 0, stream>>>(erow, cnt);
    k_scan1<<<196, 512, 0, stream>>>(cnt, rp, part);
    k_scan2<<<1, 256, 0, stream>>>(part, 196);
    k_scan3<<<196, 512, 0, stream>>>(rp, part);
    k_fill<<<3125, 256, 0, stream>>>(erow, ecol, ew, rp, fil, ep);

    k_prep_w<<<NL + 1, 256, 0, stream>>>(convW, Win, Bhi, Blo);
    k_prep_out<<<1, 256, 0, stream>>>(Wout, Bohi, Bolo);

    k_lin_in<<<GEMM_GRID, 256, 0, stream>>>(x, Bhi + (size_t)NL * DH * DH, Blo + (size_t)NL * DH * DH, bin, x0);

    for (int l = 0; l < NL; ++l) {
        const __bf16* hin = (l == 0) ? x0 : h;
        k_spmm<<<25000, 256, 0, stream>>>(hin, x0, rp, ep, a);
        k_gemm_mfma<<<GEMM_GRID, 256, 0, stream>>>(a, a, Bhi + (size_t)l * DH * DH, Blo + (size_t)l * DH * DH,
                                                   partials);
        k_stats<<<64, 256, 0, stream>>>(partials, stats + l * 256);
        k_update<<<6250, 256, 0, stream>>>(a, hin, h, stats + l * 256, gamma + l * DH, bbeta + l * DH);
    }
    k_gemm_out<<<GEMM_GRID, 256, 0, stream>>>(h, Bohi, Bolo, bout, out);
}